// Round 4
// baseline (58.702 us; speedup 1.0000x reference)
//
#include <hip/hip_runtime.h>
#include <hip/hip_bf16.h>

constexpr int KST  = 12;
constexpr int NN   = 10;
constexpr int B    = 2;
constexpr int C    = 512;
constexpr int T    = 4096;
constexpr int BAND = 12;

typedef float f32x4  __attribute__((ext_vector_type(4)));
typedef short bf16x8 __attribute__((ext_vector_type(8)));

__device__ __forceinline__ float logsig(float x) {
    return fminf(x, 0.0f) - log1pf(expf(-fabsf(x)));
}
__device__ __forceinline__ unsigned short f2bf(float f) {
    union { float f; unsigned u; } v; v.f = f;
    unsigned r = v.u + 0x7fff + ((v.u >> 16) & 1);   // RNE
    return (unsigned short)(r >> 16);
}

// ---------------------------------------------------------------------------
// Kernel 0: cast W fp32 -> bf16
// ---------------------------------------------------------------------------
__global__ __launch_bounds__(256) void cast_w(
    const float* __restrict__ W, unsigned short* __restrict__ Wh)
{
    const int i = (blockIdx.x * 256 + threadIdx.x) * 4;
    const float4 v = *(const float4*)&W[i];
    short4 o;
    o.x = (short)f2bf(v.x);
    o.y = (short)f2bf(v.y);
    o.z = (short)f2bf(v.z);
    o.w = (short)f2bf(v.w);
    *(short4*)&Wh[i] = o;
}

// ---------------------------------------------------------------------------
// Fused kernel, 3-barrier structure. Per (32-col s-tile, batch):
//   Phase 0: stage fc K-panel [s=32][k=512] -> fc_t (bf16, XOR-swizzled)
//            stage enc window (64 cols x 512 d)  -> A_t (bf16, XOR-swizzled)
//   barrier
//   Phase 1 (stage A): c[:,tile] = W @ fc + bias. Each wave: 64m x 32n,
//            16 k-steps x 8 MFMA, A-frags double-buffered from global W
//            (L2-resident), B-frags ds_read_b128 from fc_t. NO barriers.
//   barrier (fc_t dead)
//   Phase 2: c frags -> bf16 -> fc_t space (now c_t[s=32][d=512], swizzled)
//   barrier
//   Phase 3 (stage B): D[64x32] = A_t * c_t^T; diagonals k=row-col in [0,12)
//            -> logsig -> block-reduce -> atomicAdd; rows 44..53 -> negls.
// Swizzle (both LDS tiles): elem (row, x) at byte
//   row*1024 + (((x>>3) ^ (row&7))<<4) + (x&7)*2
// ---------------------------------------------------------------------------
__global__ __launch_bounds__(512) void fused_kernel(
    const unsigned short* __restrict__ Wh, const float* __restrict__ FC,
    const float* __restrict__ enc, const float* __restrict__ bias,
    float* __restrict__ negls, float* __restrict__ out)
{
    const int b  = blockIdx.y;
    const int n0 = blockIdx.x * 32;

    __shared__ unsigned short fc_t[32 * 512];  // phase 0-1: fc; phase 2-3: c
    __shared__ unsigned short A_t[64 * 512];
    __shared__ float posred[8];

    const int tid  = threadIdx.x;
    const int lane = tid & 63;
    const int w    = tid >> 6;       // 0..7
    const int l15  = lane & 15;
    const int l4   = lane >> 4;      // 0..3
    const int mw   = w * 64;

    const float* FCb  = FC  + (size_t)b * C * T;
    const float* encb = enc + (size_t)b * C * T;

    // ---------------- phase 0a: fc K-panel -> fc_t ----------------
    {
        const int k = tid;                       // 512 threads = 512 k-rows
        const float* p = FCb + (size_t)k * T + n0;
        float vals[32];
        #pragma unroll
        for (int q = 0; q < 8; ++q)
            *(float4*)&vals[q * 4] = *(const float4*)(p + q * 4);
        const int gk = k >> 3;
        const int ke = (k & 7) * 2;
        #pragma unroll
        for (int j = 0; j < 32; ++j) {
            const int off = j * 1024 + ((gk ^ (j & 7)) << 4) + ke;
            *(unsigned short*)((char*)fc_t + off) = f2bf(vals[j]);
        }
    }

    // ---------------- phase 0b: enc window -> A_t ----------------
    // cols 0..47 -> t = n0 + c (clamped at edge), cols 48..63 -> t = c - 48
    {
        const bool safe = (n0 + 48 <= T);
        const int rr    = tid >> 3;          // 0..63
        const int cbase = (tid & 7) * 8;     // 0,8,...,56
        #pragma unroll
        for (int dd = 0; dd < 8; ++dd) {
            const int d = dd * 64 + rr;
            float vals[8];
            if (cbase < 48) {
                if (safe) {
                    const float* p = encb + (size_t)d * T + n0 + cbase;
                    *(float4*)&vals[0] = *(const float4*)p;
                    *(float4*)&vals[4] = *(const float4*)(p + 4);
                } else {
                    #pragma unroll
                    for (int e = 0; e < 8; ++e) {
                        int t = n0 + cbase + e;
                        t = t < T ? t : T - 1;
                        vals[e] = encb[(size_t)d * T + t];
                    }
                }
            } else {
                const float* p = encb + (size_t)d * T + (cbase - 48);
                *(float4*)&vals[0] = *(const float4*)p;
                *(float4*)&vals[4] = *(const float4*)(p + 4);
            }
            const int gd = d >> 3;
            const int dl = (d & 7) << 1;
            #pragma unroll
            for (int e = 0; e < 8; ++e) {
                const int c = cbase + e;            // c & 7 == e
                const int off = c * 1024 + ((gd ^ e) << 4) + dl;
                *(unsigned short*)((char*)A_t + off) = f2bf(vals[e]);
            }
        }
    }
    __syncthreads();

    // ---------------- phase 1: stage A, no barriers ----------------
    f32x4 acc[4][2] = {};
    const unsigned short* Abase = Wh + (size_t)(mw + l15) * C + 8 * l4;
    const char* Bb0 = (const char*)fc_t + (size_t)l15 * 1024;
    const char* Bb1 = (const char*)fc_t + (size_t)(16 + l15) * 1024;
    const int bx = l15 & 7;   // same for row l15 and 16+l15

    bf16x8 a_cur[4];
    #pragma unroll
    for (int i = 0; i < 4; ++i)
        a_cur[i] = *(const bf16x8*)(Abase + (size_t)i * 16 * C);

    #pragma unroll
    for (int ks = 0; ks < 16; ++ks) {
        bf16x8 a_nxt[4];
        if (ks < 15) {
            #pragma unroll
            for (int i = 0; i < 4; ++i)
                a_nxt[i] = *(const bf16x8*)(Abase + (size_t)i * 16 * C + (ks + 1) * 32);
        }
        const int ga = ks * 4 + l4;
        const bf16x8 b0 = *(const bf16x8*)(Bb0 + ((ga ^ bx) << 4));
        const bf16x8 b1 = *(const bf16x8*)(Bb1 + ((ga ^ bx) << 4));
        #pragma unroll
        for (int i = 0; i < 4; ++i) {
            acc[i][0] = __builtin_amdgcn_mfma_f32_16x16x32_bf16(a_cur[i], b0, acc[i][0], 0, 0, 0);
            acc[i][1] = __builtin_amdgcn_mfma_f32_16x16x32_bf16(a_cur[i], b1, acc[i][1], 0, 0, 0);
        }
        if (ks < 15) {
            #pragma unroll
            for (int i = 0; i < 4; ++i) a_cur[i] = a_nxt[i];
        }
    }
    __syncthreads();   // fc_t reads complete everywhere

    // ---------------- phase 2: c frags -> fc_t (as c_t) ----------------
    #pragma unroll
    for (int i = 0; i < 4; ++i) {
        const int mb = mw + i * 16 + l4 * 4;     // d base (mult of 4)
        const float4 bv = *(const float4*)&bias[mb];
        const int g = mb >> 3;
        #pragma unroll
        for (int j = 0; j < 2; ++j) {
            const int sp = j * 16 + l15;
            ushort4 u;
            u.x = f2bf(acc[i][j][0] + bv.x);
            u.y = f2bf(acc[i][j][1] + bv.y);
            u.z = f2bf(acc[i][j][2] + bv.z);
            u.w = f2bf(acc[i][j][3] + bv.w);
            const int off = sp * 1024 + ((g ^ (sp & 7)) << 4) + ((mb & 4) << 1);
            *(ushort4*)((char*)fc_t + off) = u;
        }
    }
    __syncthreads();

    // ---------------- phase 3: stage B band MFMA ----------------
    const int i2 = w >> 1;               // 0..3 row-frag
    const int j2 = w & 1;                // 0..1 col-frag
    const int rg = i2 * 16 + l15;        // D row 0..63
    const int ci = (rg < 44) ? rg : ((rg < 54) ? rg + 4 : 63);
    const int sr = j2 * 16 + l15;
    const char* Abyte = (const char*)A_t + ci * 1024;
    const char* Bbyte = (const char*)fc_t + sr * 1024;
    const int ax = ci & 7, bx2 = sr & 7;

    f32x4 dacc = {};
    #pragma unroll
    for (int ks = 0; ks < 16; ++ks) {
        const int ga = ks * 4 + l4;
        const bf16x8 a2 = *(const bf16x8*)(Abyte + ((ga ^ ax) << 4));
        const bf16x8 b2 = *(const bf16x8*)(Bbyte + ((ga ^ bx2) << 4));
        dacc = __builtin_amdgcn_mfma_f32_16x16x32_bf16(a2, b2, dacc, 0, 0, 0);
    }

    float pos = 0.0f;
    const int colr = j2 * 16 + l15;
    const int scol = n0 + colr;
    #pragma unroll
    for (int r = 0; r < 4; ++r) {
        const int row = i2 * 16 + l4 * 4 + r;
        const float vv = dacc[r];
        if (row < 44) {
            const int k = row - colr;
            if (k >= 0 && k < BAND && scol + k < T) pos += logsig(vv);
        } else if (row < 54) {
            negls[((size_t)b * NN + (row - 44)) * T + scol] = logsig(-vv);
        }
    }
    #pragma unroll
    for (int off = 32; off > 0; off >>= 1) pos += __shfl_down(pos, off, 64);
    if (lane == 0) posred[w] = pos;
    __syncthreads();
    if (tid == 0) {
        float tsum = 0.0f;
        #pragma unroll
        for (int q = 0; q < 8; ++q) tsum += posred[q];
        atomicAdd(out, tsum);
    }
}

// ---------------------------------------------------------------------------
// Kernel 2: gather negatives; out += NN * sum logsig(-cont[b,n,idx]).
// ---------------------------------------------------------------------------
__global__ __launch_bounds__(256) void gather_kernel(
    const int4* __restrict__ nidx4, const float* __restrict__ negls,
    float* __restrict__ out)
{
    const int i4 = blockIdx.x * 256 + threadIdx.x;
    const int4 vv = nidx4[i4];
    const int base = i4 * 4;
    const int idxs[4] = {vv.x, vv.y, vv.z, vv.w};
    float local = 0.0f;
    #pragma unroll
    for (int e = 0; e < 4; ++e) {
        const int n = (base + e) % NN;     // layout [k][t][n], n fastest
        local += negls[(size_t)n * T + idxs[e]]
               + negls[(size_t)(NN + n) * T + idxs[e]];
    }
    #pragma unroll
    for (int off = 32; off > 0; off >>= 1) local += __shfl_down(local, off, 64);
    __shared__ float wsum[4];
    if ((threadIdx.x & 63) == 0) wsum[threadIdx.x >> 6] = local;
    __syncthreads();
    if (threadIdx.x == 0)
        atomicAdd(out, (float)NN * (wsum[0] + wsum[1] + wsum[2] + wsum[3]));
}

// ---------------------------------------------------------------------------
extern "C" void kernel_launch(void* const* d_in, const int* in_sizes, int n_in,
                              void* d_out, int out_size, void* d_ws, size_t ws_size,
                              hipStream_t stream)
{
    const float* enc  = (const float*)d_in[0];
    const float* fc   = (const float*)d_in[1];
    const float* W    = (const float*)d_in[2];
    const float* bias = (const float*)d_in[3];
    const int*   nidx = (const int*)d_in[4];
    float* out = (float*)d_out;

    unsigned short* Wh = (unsigned short*)d_ws;                       // C*C bf16
    float* negls = (float*)((char*)d_ws + (size_t)C * C * sizeof(unsigned short));

    hipMemsetAsync(out, 0, sizeof(float), stream);

    cast_w<<<C * C / (256 * 4), 256, 0, stream>>>(W, Wh);
    fused_kernel<<<dim3(T / 32, B), 512, 0, stream>>>(Wh, fc, enc, bias, negls, out);
    gather_kernel<<<KST * T * NN / (4 * 256), 256, 0, stream>>>(
        (const int4*)nidx, negls, out);
}